// Round 7
// baseline (424.317 us; speedup 1.0000x reference)
//
#include <hip/hip_runtime.h>

typedef short v8s __attribute__((ext_vector_type(8)));
typedef float v4f __attribute__((ext_vector_type(4)));
using u16 = unsigned short;

__device__ __forceinline__ u16 f2b(float f) {
  union { float f; unsigned u; } v; v.f = f;
  unsigned r = v.u + 0x7FFFu + ((v.u >> 16) & 1u);
  return (u16)(r >> 16);
}

// ---------------- LayerNorm + bf16 casts ----------------
__global__ void ln_prep(const float* __restrict__ x, const float* __restrict__ ctx,
                        const float* __restrict__ gamma, const float* __restrict__ beta,
                        float* __restrict__ xn_f, u16* __restrict__ xn_b,
                        u16* __restrict__ ctx_b)
{
  const int tid = threadIdx.x;
  if (blockIdx.y == 0) {
    const int wid = tid >> 6, lane = tid & 63;
    const int row = blockIdx.x * 4 + wid;
    const float4 xv = *(const float4*)(x + (size_t)row * 256 + lane * 4);
    float s1 = xv.x + xv.y + xv.z + xv.w;
    float s2 = xv.x*xv.x + xv.y*xv.y + xv.z*xv.z + xv.w*xv.w;
#pragma unroll
    for (int m = 32; m >= 1; m >>= 1) {
      s1 += __shfl_xor(s1, m);
      s2 += __shfl_xor(s2, m);
    }
    const float mu  = s1 * (1.0f/256.0f);
    const float var = s2 * (1.0f/256.0f) - mu*mu;
    const float rs  = rsqrtf(var + 1e-3f);
    const float4 g = *(const float4*)(gamma + lane*4);
    const float4 b = *(const float4*)(beta  + lane*4);
    float4 y;
    y.x = (xv.x-mu)*rs*g.x + b.x;
    y.y = (xv.y-mu)*rs*g.y + b.y;
    y.z = (xv.z-mu)*rs*g.z + b.z;
    y.w = (xv.w-mu)*rs*g.w + b.w;
    *(float4*)(xn_f + (size_t)row*256 + lane*4) = y;
    ushort4 yb; yb.x=f2b(y.x); yb.y=f2b(y.y); yb.z=f2b(y.z); yb.w=f2b(y.w);
    *(ushort4*)(xn_b + (size_t)row*256 + lane*4) = yb;
  } else {
    const size_t idx = (size_t)blockIdx.x * 1024 + (size_t)tid * 4;
    const float4 cv = *(const float4*)(ctx + idx);
    ushort4 cb; cb.x=f2b(cv.x); cb.y=f2b(cv.y); cb.z=f2b(cv.z); cb.w=f2b(cv.w);
    *(ushort4*)(ctx_b + idx) = cb;
  }
}

// ---------------- weight transpose + bf16 cast (LDS-tiled) ----------------
__global__ void wtrans(const float* __restrict__ wq, const float* __restrict__ wk,
                       const float* __restrict__ wv, const float* __restrict__ wp,
                       u16* __restrict__ tq, u16* __restrict__ tk,
                       u16* __restrict__ tv, u16* __restrict__ tp)
{
  const float* src; u16* dst;
  switch (blockIdx.y) {
    case 0:  src = wq; dst = tq; break;
    case 1:  src = wk; dst = tk; break;
    case 2:  src = wv; dst = tv; break;
    default: src = wp; dst = tp; break;
  }
  __shared__ float tile[64][65];
  const int t = threadIdx.x;
  const int r0 = (blockIdx.x & 3) * 64, c0 = (blockIdx.x >> 2) * 64;
  const int c = t & 63, r = t >> 6;
#pragma unroll
  for (int j = 0; j < 16; j++)
    tile[r + j*4][c] = src[(size_t)(r0 + r + j*4) * 256 + c0 + c];
  __syncthreads();
#pragma unroll
  for (int j = 0; j < 16; j++)
    dst[(size_t)(c0 + r + j*4) * 256 + r0 + c] = f2b(tile[c][r + j*4]);
}

// ---------------- q/k/v GEMM ----------------
__global__ __launch_bounds__(256) void gemm_qkv(
    const u16* __restrict__ xn_b, const u16* __restrict__ ctx_b,
    const u16* __restrict__ wqt, const u16* __restrict__ wkt, const u16* __restrict__ wvt,
    const float* __restrict__ bq, const float* __restrict__ bk, const float* __restrict__ bv,
    u16* __restrict__ qo, u16* __restrict__ ko, u16* __restrict__ vto)
{
  const int mode = blockIdx.y;
  const u16* A; const u16* Wt; const float* bias;
  if (mode == 0)      { A = xn_b;  Wt = wqt; bias = bq; }
  else if (mode == 1) { A = ctx_b; Wt = wkt; bias = bk; }
  else                { A = ctx_b; Wt = wvt; bias = bv; }
  const int wid = threadIdx.x >> 6, lane = threadIdx.x & 63;
  const int lm = lane & 15, q4 = lane >> 4;
  const int m0 = blockIdx.x * 64 + wid * 16;
  const u16* arow = A + (size_t)(m0 + lm) * 256 + q4 * 8;
  v8s af[8];
#pragma unroll
  for (int kf = 0; kf < 8; kf++) af[kf] = *(const v8s*)(arow + kf * 32);
#pragma unroll
  for (int ct = 0; ct < 16; ct++) {
    const int c = ct * 16 + lm;
    const u16* wrow = Wt + (size_t)c * 256 + q4 * 8;
    v4f acc = {0.f, 0.f, 0.f, 0.f};
#pragma unroll
    for (int kf = 0; kf < 8; kf++)
      acc = __builtin_amdgcn_mfma_f32_16x16x32_bf16(af[kf], *(const v8s*)(wrow + kf * 32), acc, 0, 0, 0);
    const float bb = bias[c];
    if (mode == 2) {
      const int b = m0 >> 12;
      const int s = (m0 & 4095) + q4 * 4;
      ushort4 pk;
      pk.x = f2b(acc[0] + bb); pk.y = f2b(acc[1] + bb);
      pk.z = f2b(acc[2] + bb); pk.w = f2b(acc[3] + bb);
      *(ushort4*)(vto + (size_t)b * 1048576 + (size_t)c * 4096 + s) = pk;
    } else {
      u16* out = (mode == 0) ? qo : ko;
#pragma unroll
      for (int r = 0; r < 4; r++)
        out[(size_t)(m0 + q4 * 4 + r) * 256 + c] = f2b(acc[r] + bb);
    }
  }
}

// ---------------- flash-style attention, v7 ----------------
// 32 q-rows/block, 4 waves, grid (128,4) = 512 blocks, full 4096-key sweep,
// direct bf16 output (no partials/combine). Per 64-key chunk:
//   phase A: wave w -> S[32q x 16 keys (w*16..)], exp -> P (LDS dbuf)
//   phase B: wave w -> O[32q x 64 ch (w*64..)] += P * V
// Register budget is the point: qf 64 + kfr/kfr2 64 + vfr 32 + addr ~15 VGPR,
// o[2][4] = 32 AGPR -> ~212 total <= 2-waves/SIMD cliff (~248). Round 6's 64-row
// version sat at 248-256 total and stayed 1 wave/SIMD. NO min-waves launch
// bound (it forces spill-heavy budgets — rounds 4/5).
__global__ __launch_bounds__(256) void attn_kernel(
    const u16* __restrict__ q, const u16* __restrict__ k,
    const u16* __restrict__ vt, u16* __restrict__ ao)
{
  __shared__ u16 P[2][32][72];   // [buf][q][key] bf16, 9.2 KB
  __shared__ float Lp[4][32];
  __shared__ float Lt[32];
  const int b   = blockIdx.y;
  const int tid = threadIdx.x;
  const int w   = tid >> 6, lane = tid & 63;
  const int lm  = lane & 15, q4 = lane >> 4;
  const int m0  = blockIdx.x * 32;
  const u16* qb = q  + (size_t)b * 4096 * 256;
  const u16* kb = k  + (size_t)b * 4096 * 256;
  const u16* vb = vt + (size_t)b * 256 * 4096;

  // Q fragments for 2 q-tiles (held all kernel, 64 VGPR)
  v8s qf[2][8];
#pragma unroll
  for (int qt = 0; qt < 2; qt++) {
    const u16* qrow = qb + (size_t)(m0 + qt * 16 + lm) * 256 + q4 * 8;
#pragma unroll
    for (int kf = 0; kf < 8; kf++) qf[qt][kf] = *(const v8s*)(qrow + kf * 32);
  }

  v4f o[2][4];
#pragma unroll
  for (int qt = 0; qt < 2; qt++)
#pragma unroll
    for (int ct = 0; ct < 4; ct++) o[qt][ct] = (v4f){0.f, 0.f, 0.f, 0.f};
  float lsum[2][4];
#pragma unroll
  for (int qt = 0; qt < 2; qt++)
#pragma unroll
    for (int r = 0; r < 4; r++) lsum[qt][r] = 0.f;

  // K fragments for chunk 0: this wave's 16-key strip
  v8s kfr[8], kfr2[8];
  {
    const u16* krow = kb + (size_t)(w * 16 + lm) * 256 + q4 * 8;
#pragma unroll
    for (int kf = 0; kf < 8; kf++) kfr[kf] = *(const v8s*)(krow + kf * 32);
  }

  for (int s0 = 0; s0 < 4096; s0 += 64) {
    const int pb = (s0 >> 6) & 1;
    // V loads for this chunk (wave's 64-ch strip x 64 keys), issued early
    v8s vfr[4][2];
#pragma unroll
    for (int ct = 0; ct < 4; ct++) {
      const u16* vrow = vb + (size_t)(w * 64 + ct * 16 + lm) * 4096 + s0 + q4 * 8;
#pragma unroll
      for (int ks = 0; ks < 2; ks++) vfr[ct][ks] = *(const v8s*)(vrow + ks * 32);
    }
    // phase A: S[32q x 16k]
    v4f sc[2];
    sc[0] = (v4f){0.f, 0.f, 0.f, 0.f};
    sc[1] = (v4f){0.f, 0.f, 0.f, 0.f};
#pragma unroll
    for (int kf = 0; kf < 8; kf++) {
      sc[0] = __builtin_amdgcn_mfma_f32_16x16x32_bf16(qf[0][kf], kfr[kf], sc[0], 0, 0, 0);
      sc[1] = __builtin_amdgcn_mfma_f32_16x16x32_bf16(qf[1][kf], kfr[kf], sc[1], 0, 0, 0);
    }
    // K prefetch for next chunk (wraps harmlessly on last iter)
    {
      const int sn = (s0 + 64) & 4095;
      const u16* krn = kb + (size_t)(sn + w * 16 + lm) * 256 + q4 * 8;
#pragma unroll
      for (int kf = 0; kf < 8; kf++) kfr2[kf] = *(const v8s*)(krn + kf * 32);
    }
    // exp -> P  (C layout: row = qt*16 + q4*4 + r, col = w*16 + lm)
#pragma unroll
    for (int qt = 0; qt < 2; qt++)
#pragma unroll
      for (int r = 0; r < 4; r++) {
        const float e = __expf(sc[qt][r] * 0.0625f);
        lsum[qt][r] += e;
        P[pb][qt * 16 + q4 * 4 + r][w * 16 + lm] = f2b(e);
      }
    __syncthreads();
    // phase B: O[32q x 64ch(w)] += P * V over the 64 keys
#pragma unroll
    for (int qt = 0; qt < 2; qt++) {
      const v8s pf0 = *(const v8s*)(&P[pb][qt * 16 + lm][q4 * 8]);
      const v8s pf1 = *(const v8s*)(&P[pb][qt * 16 + lm][32 + q4 * 8]);
#pragma unroll
      for (int ct = 0; ct < 4; ct++) {
        o[qt][ct] = __builtin_amdgcn_mfma_f32_16x16x32_bf16(pf0, vfr[ct][0], o[qt][ct], 0, 0, 0);
        o[qt][ct] = __builtin_amdgcn_mfma_f32_16x16x32_bf16(pf1, vfr[ct][1], o[qt][ct], 0, 0, 0);
      }
    }
#pragma unroll
    for (int kf = 0; kf < 8; kf++) kfr[kf] = kfr2[kf];
  }

  // l: butterfly over the 16 key-lanes; cross-wave sum via LDS
#pragma unroll
  for (int qt = 0; qt < 2; qt++)
#pragma unroll
    for (int r = 0; r < 4; r++) {
      float t = lsum[qt][r];
      t += __shfl_xor(t, 1); t += __shfl_xor(t, 2);
      t += __shfl_xor(t, 4); t += __shfl_xor(t, 8);
      lsum[qt][r] = t;
    }
  if (lm == 0) {
#pragma unroll
    for (int qt = 0; qt < 2; qt++)
#pragma unroll
      for (int r = 0; r < 4; r++) Lp[w][qt * 16 + q4 * 4 + r] = lsum[qt][r];
  }
  __syncthreads();
  if (tid < 32) Lt[tid] = 1.0f / (Lp[0][tid] + Lp[1][tid] + Lp[2][tid] + Lp[3][tid]);
  __syncthreads();

  u16* aob = ao + ((size_t)b * 4096 + m0) * 256;
#pragma unroll
  for (int qt = 0; qt < 2; qt++)
#pragma unroll
    for (int r = 0; r < 4; r++) {
      const float linv = Lt[qt * 16 + q4 * 4 + r];
      const size_t rbase = (size_t)(qt * 16 + q4 * 4 + r) * 256 + w * 64;
#pragma unroll
      for (int ct = 0; ct < 4; ct++)
        aob[rbase + ct * 16 + lm] = f2b(o[qt][ct][r] * linv);
    }
}

// ---------------- proj GEMM + bias + residual ----------------
__global__ __launch_bounds__(256) void gemm_proj(
    const u16* __restrict__ A, const u16* __restrict__ Wt, const float* __restrict__ bias,
    const float* __restrict__ xn_f, float* __restrict__ out)
{
  const int wid = threadIdx.x >> 6, lane = threadIdx.x & 63;
  const int lm = lane & 15, q4 = lane >> 4;
  const int m0 = blockIdx.x * 64 + wid * 16;
  const u16* arow = A + (size_t)(m0 + lm) * 256 + q4 * 8;
  v8s af[8];
#pragma unroll
  for (int kf = 0; kf < 8; kf++) af[kf] = *(const v8s*)(arow + kf * 32);
#pragma unroll
  for (int ct = 0; ct < 16; ct++) {
    const int c = ct * 16 + lm;
    const u16* wrow = Wt + (size_t)c * 256 + q4 * 8;
    v4f acc = {0.f, 0.f, 0.f, 0.f};
#pragma unroll
    for (int kf = 0; kf < 8; kf++)
      acc = __builtin_amdgcn_mfma_f32_16x16x32_bf16(af[kf], *(const v8s*)(wrow + kf * 32), acc, 0, 0, 0);
    const float bb = bias[c];
#pragma unroll
    for (int r = 0; r < 4; r++) {
      const size_t idx = (size_t)(m0 + q4 * 4 + r) * 256 + c;
      out[idx] = xn_f[idx] + acc[r] + bb;
    }
  }
}

extern "C" void kernel_launch(void* const* d_in, const int* in_sizes, int n_in,
                              void* d_out, int out_size, void* d_ws, size_t ws_size,
                              hipStream_t stream)
{
  (void)in_sizes; (void)n_in; (void)out_size; (void)ws_size;
  const float* inputs  = (const float*)d_in[0];
  const float* context = (const float*)d_in[1];
  const float* Wq = (const float*)d_in[2];
  const float* bq = (const float*)d_in[3];
  const float* Wk = (const float*)d_in[4];
  const float* bk = (const float*)d_in[5];
  const float* Wv = (const float*)d_in[6];
  const float* bv = (const float*)d_in[7];
  const float* Wp = (const float*)d_in[8];
  const float* bp = (const float*)d_in[9];
  const float* gamma = (const float*)d_in[10];
  const float* beta  = (const float*)d_in[11];
  float* out = (float*)d_out;

  char* p = (char*)d_ws;
  float* xn_f = (float*)p; p += (size_t)16384 * 256 * 4;
  u16* xn_b   = (u16*)p;   p += (size_t)16384 * 256 * 2;
  u16* ctx_b  = (u16*)p;   p += (size_t)16384 * 256 * 2;
  u16* qbuf   = (u16*)p;   p += (size_t)16384 * 256 * 2;
  u16* kbuf   = (u16*)p;   p += (size_t)16384 * 256 * 2;
  u16* vtbuf  = (u16*)p;   p += (size_t)16384 * 256 * 2;
  u16* wqt = (u16*)p; p += (size_t)256 * 256 * 2;
  u16* wkt = (u16*)p; p += (size_t)256 * 256 * 2;
  u16* wvt = (u16*)p; p += (size_t)256 * 256 * 2;
  u16* wpt = (u16*)p; p += (size_t)256 * 256 * 2;
  u16* aobuf = xn_b;  // xn_b dead after gemm_qkv

  ln_prep<<<dim3(4096, 2), 256, 0, stream>>>(inputs, context, gamma, beta, xn_f, xn_b, ctx_b);
  wtrans<<<dim3(16, 4), 256, 0, stream>>>(Wq, Wk, Wv, Wp, wqt, wkt, wvt, wpt);
  gemm_qkv<<<dim3(256, 3), 256, 0, stream>>>(xn_b, ctx_b, wqt, wkt, wvt, bq, bk, bv, qbuf, kbuf, vtbuf);
  attn_kernel<<<dim3(128, 4), 256, 0, stream>>>(qbuf, kbuf, vtbuf, aobuf);
  gemm_proj<<<dim3(256), 256, 0, stream>>>(aobuf, wpt, bp, xn_f, out);
}

// Round 8
// 340.941 us; speedup vs baseline: 1.2445x; 1.2445x over previous
//
#include <hip/hip_runtime.h>

typedef short v8s __attribute__((ext_vector_type(8)));
typedef float v4f __attribute__((ext_vector_type(4)));
using u16 = unsigned short;

__device__ __forceinline__ u16 f2b(float f) {
  union { float f; unsigned u; } v; v.f = f;
  unsigned r = v.u + 0x7FFFu + ((v.u >> 16) & 1u);
  return (u16)(r >> 16);
}

// async global->LDS, 16B per lane. LDS dest = uniform base + lane*16 (m104).
__device__ __forceinline__ void stage16(const u16* g, u16* l) {
  __builtin_amdgcn_global_load_lds((const __attribute__((address_space(1))) void*)g,
                                   (__attribute__((address_space(3))) void*)l,
                                   16, 0, 0);
}

// ---------------- LayerNorm + bf16 casts ----------------
__global__ void ln_prep(const float* __restrict__ x, const float* __restrict__ ctx,
                        const float* __restrict__ gamma, const float* __restrict__ beta,
                        float* __restrict__ xn_f, u16* __restrict__ xn_b,
                        u16* __restrict__ ctx_b)
{
  const int tid = threadIdx.x;
  if (blockIdx.y == 0) {
    const int wid = tid >> 6, lane = tid & 63;
    const int row = blockIdx.x * 4 + wid;
    const float4 xv = *(const float4*)(x + (size_t)row * 256 + lane * 4);
    float s1 = xv.x + xv.y + xv.z + xv.w;
    float s2 = xv.x*xv.x + xv.y*xv.y + xv.z*xv.z + xv.w*xv.w;
#pragma unroll
    for (int m = 32; m >= 1; m >>= 1) {
      s1 += __shfl_xor(s1, m);
      s2 += __shfl_xor(s2, m);
    }
    const float mu  = s1 * (1.0f/256.0f);
    const float var = s2 * (1.0f/256.0f) - mu*mu;
    const float rs  = rsqrtf(var + 1e-3f);
    const float4 g = *(const float4*)(gamma + lane*4);
    const float4 b = *(const float4*)(beta  + lane*4);
    float4 y;
    y.x = (xv.x-mu)*rs*g.x + b.x;
    y.y = (xv.y-mu)*rs*g.y + b.y;
    y.z = (xv.z-mu)*rs*g.z + b.z;
    y.w = (xv.w-mu)*rs*g.w + b.w;
    *(float4*)(xn_f + (size_t)row*256 + lane*4) = y;
    ushort4 yb; yb.x=f2b(y.x); yb.y=f2b(y.y); yb.z=f2b(y.z); yb.w=f2b(y.w);
    *(ushort4*)(xn_b + (size_t)row*256 + lane*4) = yb;
  } else {
    const size_t idx = (size_t)blockIdx.x * 1024 + (size_t)tid * 4;
    const float4 cv = *(const float4*)(ctx + idx);
    ushort4 cb; cb.x=f2b(cv.x); cb.y=f2b(cv.y); cb.z=f2b(cv.z); cb.w=f2b(cv.w);
    *(ushort4*)(ctx_b + idx) = cb;
  }
}

// ---------------- weight transpose + bf16 cast (LDS-tiled) ----------------
__global__ void wtrans(const float* __restrict__ wq, const float* __restrict__ wk,
                       const float* __restrict__ wv, const float* __restrict__ wp,
                       u16* __restrict__ tq, u16* __restrict__ tk,
                       u16* __restrict__ tv, u16* __restrict__ tp)
{
  const float* src; u16* dst;
  switch (blockIdx.y) {
    case 0:  src = wq; dst = tq; break;
    case 1:  src = wk; dst = tk; break;
    case 2:  src = wv; dst = tv; break;
    default: src = wp; dst = tp; break;
  }
  __shared__ float tile[64][65];
  const int t = threadIdx.x;
  const int r0 = (blockIdx.x & 3) * 64, c0 = (blockIdx.x >> 2) * 64;
  const int c = t & 63, r = t >> 6;
#pragma unroll
  for (int j = 0; j < 16; j++)
    tile[r + j*4][c] = src[(size_t)(r0 + r + j*4) * 256 + c0 + c];
  __syncthreads();
#pragma unroll
  for (int j = 0; j < 16; j++)
    dst[(size_t)(c0 + r + j*4) * 256 + r0 + c] = f2b(tile[c][r + j*4]);
}

// ---------------- q/k/v GEMM ----------------
__global__ __launch_bounds__(256) void gemm_qkv(
    const u16* __restrict__ xn_b, const u16* __restrict__ ctx_b,
    const u16* __restrict__ wqt, const u16* __restrict__ wkt, const u16* __restrict__ wvt,
    const float* __restrict__ bq, const float* __restrict__ bk, const float* __restrict__ bv,
    u16* __restrict__ qo, u16* __restrict__ ko, u16* __restrict__ vto)
{
  const int mode = blockIdx.y;
  const u16* A; const u16* Wt; const float* bias;
  if (mode == 0)      { A = xn_b;  Wt = wqt; bias = bq; }
  else if (mode == 1) { A = ctx_b; Wt = wkt; bias = bk; }
  else                { A = ctx_b; Wt = wvt; bias = bv; }
  const int wid = threadIdx.x >> 6, lane = threadIdx.x & 63;
  const int lm = lane & 15, q4 = lane >> 4;
  const int m0 = blockIdx.x * 64 + wid * 16;
  const u16* arow = A + (size_t)(m0 + lm) * 256 + q4 * 8;
  v8s af[8];
#pragma unroll
  for (int kf = 0; kf < 8; kf++) af[kf] = *(const v8s*)(arow + kf * 32);
#pragma unroll
  for (int ct = 0; ct < 16; ct++) {
    const int c = ct * 16 + lm;
    const u16* wrow = Wt + (size_t)c * 256 + q4 * 8;
    v4f acc = {0.f, 0.f, 0.f, 0.f};
#pragma unroll
    for (int kf = 0; kf < 8; kf++)
      acc = __builtin_amdgcn_mfma_f32_16x16x32_bf16(af[kf], *(const v8s*)(wrow + kf * 32), acc, 0, 0, 0);
    const float bb = bias[c];
    if (mode == 2) {
      const int b = m0 >> 12;
      const int s = (m0 & 4095) + q4 * 4;
      ushort4 pk;
      pk.x = f2b(acc[0] + bb); pk.y = f2b(acc[1] + bb);
      pk.z = f2b(acc[2] + bb); pk.w = f2b(acc[3] + bb);
      *(ushort4*)(vto + (size_t)b * 1048576 + (size_t)c * 4096 + s) = pk;
    } else {
      u16* out = (mode == 0) ? qo : ko;
#pragma unroll
      for (int r = 0; r < 4; r++)
        out[(size_t)(m0 + q4 * 4 + r) * 256 + c] = f2b(acc[r] + bb);
    }
  }
}

// ---------------- flash-style attention, v8 ----------------
// The r3-r7 limiter was scattered register-fragment loads (64 lanes touching
// 16 rows 512B apart): ~75 cyc/instr, ~14 B/cyc/CU at the TCP, invariant to
// occupancy. v8 stages K/V chunks into LDS with global_load_lds (contiguous
// 1024 B/instr, no VGPR round-trip) and reads MFMA fragments via ds_read_b128.
// Bank conflicts from the 512B/128B row strides are broken by a granule XOR
// swizzle (g ^= row&7), applied identically at stage (per-lane global source)
// and read -> 2-way only (free, m136). Padding is impossible with
// global_load_lds (lane-ordered dest, m104) — the swizzle replaces it.
// 64 q-rows/block, 4 waves; wave w: phase A = 16-key score strip, phase B =
// 64-ch O strip. Grid (64,4,2): key-split halves -> 512 blocks = 2 blocks/CU
// (LDS 74.7 KB -> two fit), fp32 partials + combine (r6 machinery).
__global__ __launch_bounds__(256) void attn_kernel(
    const u16* __restrict__ q, const u16* __restrict__ k,
    const u16* __restrict__ vt, float* __restrict__ Op, float* __restrict__ Lb)
{
  __shared__ u16 Ks[64 * 256];   // [key][ch-granule swizzled]  32 KB
  __shared__ u16 Vs[256 * 64];   // [ch][key-granule swizzled]  32 KB
  __shared__ u16 P[64][72];      // scores, C-layout, +8 pad     9.2 KB
  __shared__ float Lp[4][64];
  const int b   = blockIdx.y;
  const int kz  = blockIdx.z;
  const int tid = threadIdx.x;
  const int w   = tid >> 6, lane = tid & 63;
  const int lm  = lane & 15, q4 = lane >> 4;
  const int m0  = blockIdx.x * 64;
  const int base = kz * 2048;
  const u16* qb = q  + (size_t)b * 4096 * 256;
  const u16* kb = k  + (size_t)b * 4096 * 256;
  const u16* vb = vt + (size_t)b * 256 * 4096;

  // staging lane decomposition
  const int i5 = lane >> 5, i31 = lane & 31;   // K: 2 rows x 32 granules / instr
  const int i3 = lane >> 3, i7 = lane & 7;     // V: 8 ch-rows x 8 granules / instr

  // Q fragments for 4 q-tiles (held all kernel, 128 VGPR)
  v8s qf[4][8];
#pragma unroll
  for (int qt = 0; qt < 4; qt++) {
    const u16* qrow = qb + (size_t)(m0 + qt * 16 + lm) * 256 + q4 * 8;
#pragma unroll
    for (int j = 0; j < 8; j++) qf[qt][j] = *(const v8s*)(qrow + j * 32);
  }

  v4f o[4][4];
#pragma unroll
  for (int qt = 0; qt < 4; qt++)
#pragma unroll
    for (int ct = 0; ct < 4; ct++) o[qt][ct] = (v4f){0.f, 0.f, 0.f, 0.f};
  float lsum[4][4];
#pragma unroll
  for (int qt = 0; qt < 4; qt++)
#pragma unroll
    for (int r = 0; r < 4; r++) lsum[qt][r] = 0.f;

  for (int s0 = base; s0 < base + 2048; s0 += 64) {
    __syncthreads();   // all waves done reading Ks/Vs/P of previous chunk
    // ---- stage K chunk: wave w covers rows [w*16, w*16+16) ----
#pragma unroll
    for (int t = 0; t < 8; t++) {
      const int r = w * 16 + 2 * t + i5;                  // 0..63 chunk-local
      const u16* g = kb + (size_t)(s0 + r) * 256 + ((i31 ^ (r & 7)) * 8);
      stage16(g, &Ks[(w * 16 + 2 * t) * 256]);
    }
    // ---- stage V chunk: wave w covers ch [w*64, w*64+64) ----
#pragma unroll
    for (int t = 0; t < 8; t++) {
      const int ch = w * 64 + 8 * t + i3;                 // 0..255
      const u16* g = vb + (size_t)ch * 4096 + s0 + ((i7 ^ (ch & 7)) * 8);
      stage16(g, &Vs[(w * 64 + 8 * t) * 64]);
    }
    __syncthreads();   // staging visible (compiler drains vmcnt before barrier)

    // ---- phase A: S[64q x 16 keys(w)] ----
    v4f sc[4];
#pragma unroll
    for (int qt = 0; qt < 4; qt++) sc[qt] = (v4f){0.f, 0.f, 0.f, 0.f};
#pragma unroll
    for (int j = 0; j < 8; j++) {
      const int row = w * 16 + lm;                        // this wave's key strip
      const int g = ((q4 + 4 * j) ^ (lm & 7)) * 8;        // swizzled ch-granule
      const v8s kf = *(const v8s*)(&Ks[row * 256 + g]);
#pragma unroll
      for (int qt = 0; qt < 4; qt++)
        sc[qt] = __builtin_amdgcn_mfma_f32_16x16x32_bf16(qf[qt][j], kf, sc[qt], 0, 0, 0);
    }
    // exp -> P (C layout: row = qt*16 + q4*4 + r, col = w*16 + lm)
#pragma unroll
    for (int qt = 0; qt < 4; qt++)
#pragma unroll
      for (int r = 0; r < 4; r++) {
        const float e = __expf(sc[qt][r] * 0.0625f);
        lsum[qt][r] += e;
        P[qt * 16 + q4 * 4 + r][w * 16 + lm] = f2b(e);
      }
    __syncthreads();   // P visible

    // ---- phase B: O[64q x 64ch(w)] += P * V ----
#pragma unroll
    for (int qt = 0; qt < 4; qt++) {
      const v8s pf0 = *(const v8s*)(&P[qt * 16 + lm][q4 * 8]);
      const v8s pf1 = *(const v8s*)(&P[qt * 16 + lm][32 + q4 * 8]);
#pragma unroll
      for (int ct = 0; ct < 4; ct++) {
        const int ch = w * 64 + ct * 16 + lm;
        const int g0 = ((q4)     ^ (lm & 7)) * 8;         // keys q4*8..
        const int g1 = ((q4 + 4) ^ (lm & 7)) * 8;         // keys 32+q4*8..
        const v8s vf0 = *(const v8s*)(&Vs[ch * 64 + g0]);
        const v8s vf1 = *(const v8s*)(&Vs[ch * 64 + g1]);
        o[qt][ct] = __builtin_amdgcn_mfma_f32_16x16x32_bf16(pf0, vf0, o[qt][ct], 0, 0, 0);
        o[qt][ct] = __builtin_amdgcn_mfma_f32_16x16x32_bf16(pf1, vf1, o[qt][ct], 0, 0, 0);
      }
    }
  }

  // partial l: butterfly over the 16 key-lanes, then sum the 4 waves
#pragma unroll
  for (int qt = 0; qt < 4; qt++)
#pragma unroll
    for (int r = 0; r < 4; r++) {
      float t = lsum[qt][r];
      t += __shfl_xor(t, 1); t += __shfl_xor(t, 2);
      t += __shfl_xor(t, 4); t += __shfl_xor(t, 8);
      lsum[qt][r] = t;
    }
  if (lm == 0) {
#pragma unroll
    for (int qt = 0; qt < 4; qt++)
#pragma unroll
      for (int r = 0; r < 4; r++) Lp[w][qt * 16 + q4 * 4 + r] = lsum[qt][r];
  }
  __syncthreads();
  const size_t row16k = (size_t)b * 4096 + m0;
  if (tid < 64)
    Lb[(size_t)kz * 16384 + row16k + tid] = Lp[0][tid] + Lp[1][tid] + Lp[2][tid] + Lp[3][tid];

  // unnormalized fp32 partial O
  float* opb = Op + ((size_t)kz * 16384 + row16k) * 256;
#pragma unroll
  for (int qt = 0; qt < 4; qt++)
#pragma unroll
    for (int r = 0; r < 4; r++) {
      const size_t rbase = (size_t)(qt * 16 + q4 * 4 + r) * 256 + w * 64;
#pragma unroll
      for (int ct = 0; ct < 4; ct++)
        opb[rbase + ct * 16 + lm] = o[qt][ct][r];
    }
}

// ---------------- combine the two key-half partials ----------------
__global__ void attn_combine(const float* __restrict__ Op, const float* __restrict__ Lb,
                             u16* __restrict__ ao)
{
  const int wid = threadIdx.x >> 6, lane = threadIdx.x & 63;
  const size_t row = (size_t)blockIdx.x * 4 + wid;
  const float linv = 1.0f / (Lb[row] + Lb[16384 + row]);
  const float4 o0 = *(const float4*)(Op + row * 256 + lane * 4);
  const float4 o1 = *(const float4*)(Op + (16384 + row) * 256 + lane * 4);
  ushort4 rb;
  rb.x = f2b((o0.x + o1.x) * linv);
  rb.y = f2b((o0.y + o1.y) * linv);
  rb.z = f2b((o0.z + o1.z) * linv);
  rb.w = f2b((o0.w + o1.w) * linv);
  *(ushort4*)(ao + row * 256 + lane * 4) = rb;
}

// ---------------- proj GEMM + bias + residual ----------------
__global__ __launch_bounds__(256) void gemm_proj(
    const u16* __restrict__ A, const u16* __restrict__ Wt, const float* __restrict__ bias,
    const float* __restrict__ xn_f, float* __restrict__ out)
{
  const int wid = threadIdx.x >> 6, lane = threadIdx.x & 63;
  const int lm = lane & 15, q4 = lane >> 4;
  const int m0 = blockIdx.x * 64 + wid * 16;
  const u16* arow = A + (size_t)(m0 + lm) * 256 + q4 * 8;
  v8s af[8];
#pragma unroll
  for (int kf = 0; kf < 8; kf++) af[kf] = *(const v8s*)(arow + kf * 32);
#pragma unroll
  for (int ct = 0; ct < 16; ct++) {
    const int c = ct * 16 + lm;
    const u16* wrow = Wt + (size_t)c * 256 + q4 * 8;
    v4f acc = {0.f, 0.f, 0.f, 0.f};
#pragma unroll
    for (int kf = 0; kf < 8; kf++)
      acc = __builtin_amdgcn_mfma_f32_16x16x32_bf16(af[kf], *(const v8s*)(wrow + kf * 32), acc, 0, 0, 0);
    const float bb = bias[c];
#pragma unroll
    for (int r = 0; r < 4; r++) {
      const size_t idx = (size_t)(m0 + q4 * 4 + r) * 256 + c;
      out[idx] = xn_f[idx] + acc[r] + bb;
    }
  }
}

extern "C" void kernel_launch(void* const* d_in, const int* in_sizes, int n_in,
                              void* d_out, int out_size, void* d_ws, size_t ws_size,
                              hipStream_t stream)
{
  (void)in_sizes; (void)n_in; (void)out_size; (void)ws_size;
  const float* inputs  = (const float*)d_in[0];
  const float* context = (const float*)d_in[1];
  const float* Wq = (const float*)d_in[2];
  const float* bq = (const float*)d_in[3];
  const float* Wk = (const float*)d_in[4];
  const float* bk = (const float*)d_in[5];
  const float* Wv = (const float*)d_in[6];
  const float* bv = (const float*)d_in[7];
  const float* Wp = (const float*)d_in[8];
  const float* bp = (const float*)d_in[9];
  const float* gamma = (const float*)d_in[10];
  const float* beta  = (const float*)d_in[11];
  float* out = (float*)d_out;

  char* p = (char*)d_ws;
  float* xn_f = (float*)p; p += (size_t)16384 * 256 * 4;
  u16* xn_b   = (u16*)p;   p += (size_t)16384 * 256 * 2;
  u16* ctx_b  = (u16*)p;   p += (size_t)16384 * 256 * 2;
  u16* qbuf   = (u16*)p;   p += (size_t)16384 * 256 * 2;
  u16* kbuf   = (u16*)p;   p += (size_t)16384 * 256 * 2;
  u16* vtbuf  = (u16*)p;   p += (size_t)16384 * 256 * 2;
  u16* wqt = (u16*)p; p += (size_t)256 * 256 * 2;
  u16* wkt = (u16*)p; p += (size_t)256 * 256 * 2;
  u16* wvt = (u16*)p; p += (size_t)256 * 256 * 2;
  u16* wpt = (u16*)p; p += (size_t)256 * 256 * 2;
  float* Opart = (float*)p; p += (size_t)2 * 16384 * 256 * 4;   // 32 MB
  float* Lpart = (float*)p; p += (size_t)2 * 16384 * 4;         // 128 KB
  u16* aobuf = xn_b;  // xn_b dead after gemm_qkv

  ln_prep<<<dim3(4096, 2), 256, 0, stream>>>(inputs, context, gamma, beta, xn_f, xn_b, ctx_b);
  wtrans<<<dim3(16, 4), 256, 0, stream>>>(Wq, Wk, Wv, Wp, wqt, wkt, wvt, wpt);
  gemm_qkv<<<dim3(256, 3), 256, 0, stream>>>(xn_b, ctx_b, wqt, wkt, wvt, bq, bk, bv, qbuf, kbuf, vtbuf);
  attn_kernel<<<dim3(64, 4, 2), 256, 0, stream>>>(qbuf, kbuf, vtbuf, Opart, Lpart);
  attn_combine<<<dim3(4096), 256, 0, stream>>>(Opart, Lpart, aobuf);
  gemm_proj<<<dim3(256), 256, 0, stream>>>(aobuf, wpt, bp, xn_f, out);
}